// Round 4
// baseline (521.208 us; speedup 1.0000x reference)
//
#include <hip/hip_runtime.h>
#include <climits>
#include <math.h>

#define Bc   2
#define Tc   2048
#define Dc   2048
#define Nc   16
#define KHc  8
#define Hc   128
#define Sc   2048

constexpr float EPSc   = 1e-6f;
constexpr float KMASKc = -0.7f * 3.4028234663852886e38f;
constexpr float SCALEc = 0.08838834764831843f;    // 1/sqrt(128)
constexpr float SCALE2 = 0.1275174477984469f;     // SCALEc * log2(e)

typedef short short8 __attribute__((ext_vector_type(8)));
typedef float float4v __attribute__((ext_vector_type(4)));

union U16x8 { uint4 u; short8 s8; unsigned short us[8]; };

__device__ __forceinline__ unsigned short f2bf(float f) {
    union { float f; unsigned u; } v; v.f = f;
    unsigned r = v.u + 0x7FFFu + ((v.u >> 16) & 1u);
    return (unsigned short)(r >> 16);
}
__device__ __forceinline__ float bf2f(unsigned short u) {
    union { unsigned u; float f; } v; v.u = ((unsigned)u) << 16;
    return v.f;
}

// ---------------------------------------------------------------------------
// meta[b] = argmax(seg) first index; meta[Bc+b] = start
// ---------------------------------------------------------------------------
__global__ void meta_kernel(const int* __restrict__ seg,
                            const int* __restrict__ start_ind,
                            int* __restrict__ meta)
{
    int b = blockIdx.x;
    __shared__ int s_max, s_amax, s_nz;
    if (threadIdx.x == 0) { s_max = INT_MIN; s_amax = Tc; s_nz = Tc; }
    __syncthreads();
    int lmax = INT_MIN;
    for (int t = threadIdx.x; t < Tc; t += blockDim.x)
        lmax = max(lmax, seg[b * Tc + t]);
    atomicMax(&s_max, lmax);
    __syncthreads();
    int mv = s_max;
    int lamax = Tc, lnz = Tc;
    for (int t = threadIdx.x; t < Tc; t += blockDim.x) {
        int v = seg[b * Tc + t];
        if (v == mv) lamax = min(lamax, t);
        if (v != 0)  lnz   = min(lnz, t);
    }
    atomicMin(&s_amax, lamax);
    atomicMin(&s_nz, lnz);
    __syncthreads();
    if (threadIdx.x == 0) {
        meta[b] = s_amax;
        int st = start_ind[b];
        meta[Bc + b] = (st < 0) ? s_nz : st;
    }
}

// ---------------------------------------------------------------------------
// cast fp32 -> bf16, 8 elems/thread
// ---------------------------------------------------------------------------
__global__ void cast_bf16(const float* __restrict__ in, unsigned short* __restrict__ out)
{
    size_t base = ((size_t)blockIdx.x * 256 + threadIdx.x) * 8;
    float4 a = *(const float4*)&in[base];
    float4 b = *(const float4*)&in[base + 4];
    U16x8 o;
    o.us[0] = f2bf(a.x); o.us[1] = f2bf(a.y); o.us[2] = f2bf(a.z); o.us[3] = f2bf(a.w);
    o.us[4] = f2bf(b.x); o.us[5] = f2bf(b.y); o.us[6] = f2bf(b.z); o.us[7] = f2bf(b.w);
    *(uint4*)&out[base] = o.u;
}

// ---------------------------------------------------------------------------
// K cache fill: only rows OUTSIDE [cur, cur+T) (fresh rows come from norm_rope)
// ---------------------------------------------------------------------------
__global__ void fill_kcache(const float* __restrict__ kc, unsigned short* __restrict__ Kall,
                            const int* __restrict__ cur_ptr)
{
    int cur = cur_ptr[0];
    size_t base = ((size_t)blockIdx.x * 256 + threadIdx.x) * 8;
    int s = (int)((base >> 10) & (Sc - 1));     // KHc*Hc = 1024 elems per s
    if (s >= cur && s < cur + Tc) return;
    float4 a = *(const float4*)&kc[base];
    float4 b = *(const float4*)&kc[base + 4];
    U16x8 o;
    o.us[0] = f2bf(a.x); o.us[1] = f2bf(a.y); o.us[2] = f2bf(a.z); o.us[3] = f2bf(a.w);
    o.us[4] = f2bf(b.x); o.us[5] = f2bf(b.y); o.us[6] = f2bf(b.z); o.us[7] = f2bf(b.w);
    *(uint4*)&Kall[base] = o.u;
}

// ---------------------------------------------------------------------------
// transpose + cast: in fp32 [R][C] -> out bf16 [C][R]
// ---------------------------------------------------------------------------
__global__ __launch_bounds__(256) void transpose_cast(const float* __restrict__ in,
                                                      unsigned short* __restrict__ out,
                                                      int R, int C)
{
    __shared__ float tile[32][33];
    int tid = threadIdx.x;
    int c0 = blockIdx.x * 32, r0 = blockIdx.y * 32;
#pragma unroll
    for (int i = 0; i < 4; ++i) {
        int row = (tid >> 5) + i * 8, col = tid & 31;
        tile[row][col] = in[(size_t)(r0 + row) * C + c0 + col];
    }
    __syncthreads();
#pragma unroll
    for (int i = 0; i < 4; ++i) {
        int rowo = (tid >> 5) + i * 8, colo = tid & 31;
        out[(size_t)(c0 + rowo) * R + r0 + colo] = f2bf(tile[colo][rowo]);
    }
}

// ---------------------------------------------------------------------------
// V transpose direct: Vt[b][kh][h][s] <- fresh (QKVh, post-GEMM V) or v_cache
// ---------------------------------------------------------------------------
__global__ void vtrans2(const unsigned short* __restrict__ QKVh,
                        const float* __restrict__ vc,
                        unsigned short* __restrict__ Vt,
                        const int* __restrict__ cur_ptr)
{
    int gid = blockIdx.x * 256 + threadIdx.x;        // 524288 total
    int h  = gid & 127;
    int s8 = ((gid >> 7) & 255) * 8;
    int kh = (gid >> 15) & 7;
    int b  = gid >> 18;
    int cur = cur_ptr[0], curT = cur + Tc;
    unsigned short tmp[8];
#pragma unroll
    for (int e = 0; e < 8; ++e) {
        int s = s8 + e;
        unsigned short v;
        if (s >= cur && s < curT)
            v = QKVh[(size_t)(b * Tc + (s - cur)) * 4096 + 3072 + kh * Hc + h];
        else
            v = f2bf(vc[((size_t)(b * Sc + s) * KHc + kh) * Hc + h]);
        tmp[e] = v;
    }
    *(uint4*)&Vt[(((size_t)b * KHc + kh) * Hc + h) * Sc + s8] = *(uint4*)tmp;
}

// ---------------------------------------------------------------------------
// bf16 MFMA GEMM (m97 structure): C[M,N] = A[M,K] * BT[N,K]^T.
// ---------------------------------------------------------------------------
__global__ __launch_bounds__(256, 2) void gemm_mfma(const unsigned short* __restrict__ A,
                                                    const unsigned short* __restrict__ BT,
                                                    void* __restrict__ Cout,
                                                    int M, int N, int K, int out_fp32)
{
    __shared__ __align__(16) unsigned short As[128 * 32];
    __shared__ __align__(16) unsigned short Bs[128 * 32];
    int tid = threadIdx.x;
    int lane = tid & 63, w = tid >> 6;
    int quad = lane >> 4, l15 = lane & 15;
    int bm = blockIdx.y * 128, bn = blockIdx.x * 128;
    int wm = (w >> 1) * 64, wn = (w & 1) * 64;

    int srow = lane >> 2;
    int pl   = lane & 3;
    int sw   = (quad ^ ((l15 >> 1) & 3)) * 8;

    float4v acc[16];
#pragma unroll
    for (int i = 0; i < 16; ++i) acc[i] = (float4v)0.f;

    for (int k0 = 0; k0 < K; k0 += 32) {
        __syncthreads();
#pragma unroll
        for (int c = 0; c < 2; ++c) {
            int j = w * 2 + c;
            int row = j * 16 + srow;
            int pg = pl ^ ((row >> 1) & 3);
            __builtin_amdgcn_global_load_lds(
                (__attribute__((address_space(1))) void*)(A + (size_t)(bm + row) * K + k0 + pg * 8),
                (__attribute__((address_space(3))) void*)(As + j * 512), 16, 0, 0);
            __builtin_amdgcn_global_load_lds(
                (__attribute__((address_space(1))) void*)(BT + (size_t)(bn + row) * K + k0 + pg * 8),
                (__attribute__((address_space(3))) void*)(Bs + j * 512), 16, 0, 0);
        }
        __syncthreads();
        short8 af[4];
#pragma unroll
        for (int mi = 0; mi < 4; ++mi)
            af[mi] = *(const short8*)&As[(wm + mi * 16 + l15) * 32 + sw];
#pragma unroll
        for (int ni = 0; ni < 4; ++ni) {
            short8 bf = *(const short8*)&Bs[(wn + ni * 16 + l15) * 32 + sw];
#pragma unroll
            for (int mi = 0; mi < 4; ++mi)
                acc[mi * 4 + ni] = __builtin_amdgcn_mfma_f32_16x16x32_bf16(af[mi], bf, acc[mi * 4 + ni], 0, 0, 0);
        }
    }

#pragma unroll
    for (int mi = 0; mi < 4; ++mi)
#pragma unroll
        for (int ni = 0; ni < 4; ++ni)
#pragma unroll
            for (int reg = 0; reg < 4; ++reg) {
                int row = bm + wm + mi * 16 + quad * 4 + reg;
                int col = bn + wn + ni * 16 + l15;
                float v = acc[mi * 4 + ni][reg];
                if (out_fp32) ((float*)Cout)[(size_t)row * N + col] = v;
                else ((unsigned short*)Cout)[(size_t)row * N + col] = f2bf(v);
            }
}

// ---------------------------------------------------------------------------
// RMSNorm + RoPE on fused QKV buffer (ld=4096). slot 0..15: Q in-place;
// 16..23: K -> Kall[cur+t].  (V handled by vtrans2.)
// ---------------------------------------------------------------------------
__global__ __launch_bounds__(256) void norm_rope(unsigned short* __restrict__ QKVh,
                                                 unsigned short* __restrict__ Kall,
                                                 const float* __restrict__ qw,
                                                 const float* __restrict__ kw,
                                                 const int* __restrict__ seg,
                                                 const int* __restrict__ meta,
                                                 const int* __restrict__ cur_ptr)
{
    int rowid = blockIdx.x * 4 + (threadIdx.x >> 6);
    int lane = threadIdx.x & 63;
    int hh = rowid % 24;
    int bt = rowid / 24;
    int t = bt & (Tc - 1);
    int b = bt >> 11;
    int cur = cur_ptr[0];

    const unsigned short* in;
    unsigned short* out;
    const float* wt;
    if (hh < 16) {
        unsigned short* p = QKVh + (size_t)bt * 4096 + hh * Hc;
        in = p; out = p; wt = qw;
    } else {
        int kh = hh - 16;
        in = QKVh + (size_t)bt * 4096 + 2048 + kh * Hc;
        out = Kall + (((size_t)b * Sc + cur + t) * KHc + kh) * Hc;
        wt = kw;
    }
    float v1 = bf2f(in[lane]), v2 = bf2f(in[lane + 64]);
    float ssq = v1 * v1 + v2 * v2;
#pragma unroll
    for (int off = 1; off < 64; off <<= 1) ssq += __shfl_xor(ssq, off);
    float rinv = rsqrtf(ssq * (1.0f / Hc) + EPSc);

    int sg = seg[bt];
    long long pos = (sg != 0) ? (long long)(t - meta[b]) : (long long)(1 << 30);
    float posf = (float)(pos + (long long)cur);
    float inv_freq = exp2f(-(float)lane * (19.931568569324174f / 64.0f));
    float s, c;
    sincosf(posf * inv_freq, &s, &c);

    float n1 = wt[lane] * v1 * rinv;
    float n2 = wt[lane + 64] * v2 * rinv;
    out[lane]      = f2bf(n1 * c - n2 * s);
    out[lane + 64] = f2bf(n2 * c + n1 * s);
}

// ---------------------------------------------------------------------------
// MFMA flash attention, fixed-max softmax (|score| <= 11.4 by Cauchy-Schwarz
// after RMSNorm, so exp2 never overflows) + register-prefetch double buffer.
// Block: 256 thr, 128 q-rows, S-chunks of 64, causal chunk skip + qt pairing.
// ---------------------------------------------------------------------------
__global__ __launch_bounds__(256, 2) void flash_mfma(const unsigned short* __restrict__ Qb,
                                                     const unsigned short* __restrict__ Kall,
                                                     const unsigned short* __restrict__ Vt,
                                                     const int* __restrict__ seg,
                                                     const int* __restrict__ meta,
                                                     const int* __restrict__ cur_ptr,
                                                     unsigned short* __restrict__ Ob)
{
    __shared__ __align__(16) unsigned short Ks[64 * 136];    // [s][h]
    __shared__ __align__(16) unsigned short Vs[128 * 72];    // [h][s]
    __shared__ __align__(16) unsigned short Ps[128 * 72];    // [qrow][s]

    int tid = threadIdx.x;
    int lane = tid & 63, w = tid >> 6;
    int quad = lane >> 4, l15 = lane & 15;
    int bid = blockIdx.x;
    int raw = bid & 15;
    int n  = (bid >> 4) & 15;
    int b  = bid >> 8;
    int qt = (b == 0) ? raw : (15 - raw);
    int kh = n >> 1;
    int cur = cur_ptr[0];
    int startb = meta[Bc + b];
    int curT = cur + Tc;
    int t0 = qt * 128 + w * 32;

    // Q fragments (A-layout)
    short8 qf[2][4];
#pragma unroll
    for (int mi = 0; mi < 2; ++mi)
#pragma unroll
        for (int ks = 0; ks < 4; ++ks) {
            int row = t0 + mi * 16 + l15;
            U16x8 u;
            u.u = *(const uint4*)&Qb[(size_t)(b * Tc + row) * 4096 + n * Hc + ks * 32 + quad * 8];
            qf[mi][ks] = u.s8;
        }

    int code = 0, ct[8];
#pragma unroll
    for (int mi = 0; mi < 2; ++mi)
#pragma unroll
        for (int reg = 0; reg < 4; ++reg) {
            int idx = mi * 4 + reg;
            int trow = t0 + mi * 16 + quad * 4 + reg;
            int sg = seg[b * Tc + trow];
            int cls = (sg == 0) ? 0 : ((sg == 1) ? 1 : 2);
            code |= cls << (2 * idx);
            ct[idx] = cur + trow;
        }
    bool allseg1 = (code == 0x5555);

    float lsum[8];
#pragma unroll
    for (int i = 0; i < 8; ++i) lsum[i] = 0.f;
    float4v o[16];
#pragma unroll
    for (int i = 0; i < 16; ++i) o[i] = (float4v)0.f;

    int s_end = min(Sc, cur + qt * 128 + 128);
    int nch = (s_end + 63) >> 6;

    const size_t kbase = (size_t)b * Sc * KHc * Hc + (size_t)kh * Hc;
    const size_t vbase = ((size_t)b * KHc + kh) * (size_t)Hc * Sc;

    uint4 kreg[4], vreg[4];
    // rows/cols for staging
    int krow[4], khp[4], vh[4], vhp[4];
#pragma unroll
    for (int i = 0; i < 4; ++i) {
        int c = tid + 256 * i;
        krow[i] = c >> 4; khp[i] = c & 15;
        vh[i] = c >> 3;   vhp[i] = c & 7;
    }

#define LOADKV(S0)                                                                     \
    {                                                                                  \
        int s0c = (S0);                                                                \
        _Pragma("unroll")                                                              \
        for (int i = 0; i < 4; ++i) {                                                  \
            int sg_ = min(s0c + krow[i], Sc - 1);                                      \
            kreg[i] = *(const uint4*)&Kall[kbase + (size_t)sg_ * (KHc * Hc) + khp[i] * 8]; \
            int sv_ = min(s0c + vhp[i] * 8, Sc - 8);                                   \
            vreg[i] = *(const uint4*)&Vt[vbase + (size_t)vh[i] * Sc + sv_];            \
        }                                                                              \
    }
#define STOREKV()                                                                      \
    {                                                                                  \
        _Pragma("unroll")                                                              \
        for (int i = 0; i < 4; ++i) {                                                  \
            *(uint4*)&Ks[krow[i] * 136 + khp[i] * 8] = kreg[i];                        \
            *(uint4*)&Vs[vh[i] * 72 + vhp[i] * 8] = vreg[i];                           \
        }                                                                              \
    }

    LOADKV(0);
    STOREKV();
    __syncthreads();

    for (int c = 0; c < nch; ++c) {
        int s0 = c * 64;
        bool more = (c + 1 < nch);
        if (more) LOADKV(s0 + 64);          // prefetch next chunk into regs

        // QK^T
        float4v sacc[2][4];
#pragma unroll
        for (int mi = 0; mi < 2; ++mi)
#pragma unroll
            for (int j = 0; j < 4; ++j) sacc[mi][j] = (float4v)0.f;
#pragma unroll
        for (int j = 0; j < 4; ++j) {
#pragma unroll
            for (int ks = 0; ks < 4; ++ks) {
                short8 kf = *(const short8*)&Ks[(j * 16 + l15) * 136 + ks * 32 + quad * 8];
                sacc[0][j] = __builtin_amdgcn_mfma_f32_16x16x32_bf16(qf[0][ks], kf, sacc[0][j], 0, 0, 0);
                sacc[1][j] = __builtin_amdgcn_mfma_f32_16x16x32_bf16(qf[1][ks], kf, sacc[1][j], 0, 0, 0);
            }
        }

        bool fullok = allseg1 && (s0 >= startb) && (s0 + 63 <= cur + t0) && (s0 + 63 < curT);

        // fixed-max softmax: p = exp2(score * SCALE2); accumulate l per lane
#pragma unroll
        for (int mi = 0; mi < 2; ++mi) {
#pragma unroll
            for (int reg = 0; reg < 4; ++reg) {
                int idx = mi * 4 + reg;
                int prow = w * 32 + mi * 16 + quad * 4 + reg;
                if (fullok) {
#pragma unroll
                    for (int j = 0; j < 4; ++j) {
                        float p = exp2f(sacc[mi][j][reg] * SCALE2);
                        lsum[idx] += p;
                        Ps[prow * 72 + j * 16 + l15] = f2bf(p);
                    }
                } else {
                    int ctv = ct[idx];
                    int clsv = (code >> (2 * idx)) & 3;
#pragma unroll
                    for (int j = 0; j < 4; ++j) {
                        int s = s0 + j * 16 + l15;
                        int kvseg = (s >= startb && s < curT) ? 1 : 0;
                        bool ok = (s <= ctv) && (clsv == kvseg);
                        float arg = ok ? sacc[mi][j][reg] * SCALE2 : -1e30f;
                        float p = exp2f(arg);
                        lsum[idx] += p;
                        Ps[prow * 72 + j * 16 + l15] = f2bf(p);
                    }
                }
            }
        }

        // PV
#pragma unroll
        for (int kk = 0; kk < 2; ++kk) {
            short8 pf0 = *(const short8*)&Ps[(w * 32 + l15) * 72 + kk * 32 + quad * 8];
            short8 pf1 = *(const short8*)&Ps[(w * 32 + 16 + l15) * 72 + kk * 32 + quad * 8];
#pragma unroll
            for (int nt = 0; nt < 8; ++nt) {
                short8 vf = *(const short8*)&Vs[(nt * 16 + l15) * 72 + kk * 32 + quad * 8];
                o[nt]     = __builtin_amdgcn_mfma_f32_16x16x32_bf16(pf0, vf, o[nt], 0, 0, 0);
                o[8 + nt] = __builtin_amdgcn_mfma_f32_16x16x32_bf16(pf1, vf, o[8 + nt], 0, 0, 0);
            }
        }

        if (more) {
            __syncthreads();
            STOREKV();
            __syncthreads();
        }
    }

    // final l reduction across the 16 lanes of each quad-row
#pragma unroll
    for (int idx = 0; idx < 8; ++idx) {
        float l = lsum[idx];
        l += __shfl_xor(l, 1);
        l += __shfl_xor(l, 2);
        l += __shfl_xor(l, 4);
        l += __shfl_xor(l, 8);
        lsum[idx] = (l > 0.f) ? (1.0f / l) : 0.f;
    }

#pragma unroll
    for (int mi = 0; mi < 2; ++mi)
#pragma unroll
        for (int reg = 0; reg < 4; ++reg) {
            float linv = lsum[mi * 4 + reg];
            int trow = t0 + mi * 16 + quad * 4 + reg;
            size_t base = ((size_t)(b * Tc + trow) * Nc + n) * Hc;
#pragma unroll
            for (int nt = 0; nt < 8; ++nt)
                Ob[base + nt * 16 + l15] = f2bf(o[mi * 8 + nt][reg] * linv);
        }
}

// ---------------------------------------------------------------------------
extern "C" void kernel_launch(void* const* d_in, const int* in_sizes, int n_in,
                              void* d_out, int out_size, void* d_ws, size_t ws_size,
                              hipStream_t stream)
{
    const float* x        = (const float*)d_in[0];
    const float* q_w      = (const float*)d_in[1];
    const float* k_w      = (const float*)d_in[2];
    const float* v_w      = (const float*)d_in[3];
    const float* o_w      = (const float*)d_in[4];
    const float* q_norm_w = (const float*)d_in[5];
    const float* k_norm_w = (const float*)d_in[6];
    const float* k_cache  = (const float*)d_in[7];
    const float* v_cache  = (const float*)d_in[8];
    const int*   seg      = (const int*)d_in[9];
    const int*   startind = (const int*)d_in[10];
    const int*   cur_ptr  = (const int*)d_in[11];
    (void)in_sizes; (void)n_in; (void)out_size; (void)ws_size;

    char* base = (char*)d_ws;
    int* meta = (int*)base;                                          //      1024 B
    unsigned short* QKVh = (unsigned short*)(base + 1024);           // 33.55 MB [4096][4096]
    unsigned short* Kall = (unsigned short*)(base + 33555456);       //  8.39 MB [B][S][KH][H]
    unsigned short* Vt   = (unsigned short*)(base + 41944064);       //  8.39 MB [B][KH][H][S]
    unsigned short* xb   = (unsigned short*)(base + 50332672);       // 16.78 MB [4096][2048]; reused as Ob
    unsigned short* qkvwT= (unsigned short*)(base + 67109888);       // 16.78 MB [4096][2048] (Q|K|V rows)
    unsigned short* owT  = (unsigned short*)(base + 83887104);       //  8.39 MB [2048][2048]
    unsigned short* Ob   = xb;

    meta_kernel<<<Bc, 256, 0, stream>>>(seg, startind, meta);

    cast_bf16<<<4096, 256, 0, stream>>>(x, xb);
    transpose_cast<<<dim3(64, 64), 256, 0, stream>>>(q_w, qkvwT, Dc, Nc * Hc);
    transpose_cast<<<dim3(32, 64), 256, 0, stream>>>(k_w, qkvwT + (size_t)2048 * 2048, Dc, KHc * Hc);
    transpose_cast<<<dim3(32, 64), 256, 0, stream>>>(v_w, qkvwT + (size_t)3072 * 2048, Dc, KHc * Hc);
    transpose_cast<<<dim3(64, 64), 256, 0, stream>>>(o_w, owT, Nc * Hc, Dc);

    // fused QKV projection: [4096 x 2048] @ [2048 x 4096]
    gemm_mfma<<<dim3(32, 32), 256, 0, stream>>>(xb, qkvwT, QKVh, Bc * Tc, 4096, Dc, 0);

    norm_rope<<<Bc * Tc * 24 / 4, 256, 0, stream>>>(QKVh, Kall,
                                                    q_norm_w, k_norm_w, seg, meta, cur_ptr);

    fill_kcache<<<2048, 256, 0, stream>>>(k_cache, Kall, cur_ptr);
    vtrans2<<<2048, 256, 0, stream>>>(QKVh, v_cache, Vt, cur_ptr);

    flash_mfma<<<Bc * Nc * (Tc / 128), 256, 0, stream>>>(QKVh, Kall, Vt, seg, meta, cur_ptr, Ob);

    gemm_mfma<<<dim3(16, 32), 256, 0, stream>>>(Ob, owT, d_out, Bc * Tc, Dc, Nc * Hc, 1);
}

// Round 5
// 422.897 us; speedup vs baseline: 1.2325x; 1.2325x over previous
//
#include <hip/hip_runtime.h>
#include <climits>
#include <math.h>

#define Bc   2
#define Tc   2048
#define Dc   2048
#define Nc   16
#define KHc  8
#define Hc   128
#define Sc   2048

constexpr float EPSc   = 1e-6f;
constexpr float SCALE2 = 0.1275174477984469f;     // (1/sqrt(128)) * log2(e)

typedef short short8 __attribute__((ext_vector_type(8)));
typedef float float4v __attribute__((ext_vector_type(4)));

union U16x8 { uint4 u; short8 s8; unsigned short us[8]; };

__device__ __forceinline__ unsigned short f2bf(float f) {
    union { float f; unsigned u; } v; v.f = f;
    unsigned r = v.u + 0x7FFFu + ((v.u >> 16) & 1u);
    return (unsigned short)(r >> 16);
}
__device__ __forceinline__ float bf2f(unsigned short u) {
    union { unsigned u; float f; } v; v.u = ((unsigned)u) << 16;
    return v.f;
}

// ---------------------------------------------------------------------------
// meta[b] = argmax(seg) first index; meta[Bc+b] = start
// ---------------------------------------------------------------------------
__global__ void meta_kernel(const int* __restrict__ seg,
                            const int* __restrict__ start_ind,
                            int* __restrict__ meta)
{
    int b = blockIdx.x;
    __shared__ int s_max, s_amax, s_nz;
    if (threadIdx.x == 0) { s_max = INT_MIN; s_amax = Tc; s_nz = Tc; }
    __syncthreads();
    int lmax = INT_MIN;
    for (int t = threadIdx.x; t < Tc; t += blockDim.x)
        lmax = max(lmax, seg[b * Tc + t]);
    atomicMax(&s_max, lmax);
    __syncthreads();
    int mv = s_max;
    int lamax = Tc, lnz = Tc;
    for (int t = threadIdx.x; t < Tc; t += blockDim.x) {
        int v = seg[b * Tc + t];
        if (v == mv) lamax = min(lamax, t);
        if (v != 0)  lnz   = min(lnz, t);
    }
    atomicMin(&s_amax, lamax);
    atomicMin(&s_nz, lnz);
    __syncthreads();
    if (threadIdx.x == 0) {
        meta[b] = s_amax;
        int st = start_ind[b];
        meta[Bc + b] = (st < 0) ? s_nz : st;
    }
}

// ---------------------------------------------------------------------------
__global__ void cast_bf16(const float* __restrict__ in, unsigned short* __restrict__ out)
{
    size_t base = ((size_t)blockIdx.x * 256 + threadIdx.x) * 8;
    float4 a = *(const float4*)&in[base];
    float4 b = *(const float4*)&in[base + 4];
    U16x8 o;
    o.us[0] = f2bf(a.x); o.us[1] = f2bf(a.y); o.us[2] = f2bf(a.z); o.us[3] = f2bf(a.w);
    o.us[4] = f2bf(b.x); o.us[5] = f2bf(b.y); o.us[6] = f2bf(b.z); o.us[7] = f2bf(b.w);
    *(uint4*)&out[base] = o.u;
}

// ---------------------------------------------------------------------------
// K cache fill: only rows OUTSIDE [cur, cur+T)
// ---------------------------------------------------------------------------
__global__ void fill_kcache(const float* __restrict__ kc, unsigned short* __restrict__ Kall,
                            const int* __restrict__ cur_ptr)
{
    int cur = cur_ptr[0];
    size_t base = ((size_t)blockIdx.x * 256 + threadIdx.x) * 8;
    int s = (int)((base >> 10) & (Sc - 1));
    if (s >= cur && s < cur + Tc) return;
    float4 a = *(const float4*)&kc[base];
    float4 b = *(const float4*)&kc[base + 4];
    U16x8 o;
    o.us[0] = f2bf(a.x); o.us[1] = f2bf(a.y); o.us[2] = f2bf(a.z); o.us[3] = f2bf(a.w);
    o.us[4] = f2bf(b.x); o.us[5] = f2bf(b.y); o.us[6] = f2bf(b.z); o.us[7] = f2bf(b.w);
    *(uint4*)&Kall[base] = o.u;
}

// ---------------------------------------------------------------------------
__global__ __launch_bounds__(256) void transpose_cast(const float* __restrict__ in,
                                                      unsigned short* __restrict__ out,
                                                      int R, int C)
{
    __shared__ float tile[32][33];
    int tid = threadIdx.x;
    int c0 = blockIdx.x * 32, r0 = blockIdx.y * 32;
#pragma unroll
    for (int i = 0; i < 4; ++i) {
        int row = (tid >> 5) + i * 8, col = tid & 31;
        tile[row][col] = in[(size_t)(r0 + row) * C + c0 + col];
    }
    __syncthreads();
#pragma unroll
    for (int i = 0; i < 4; ++i) {
        int rowo = (tid >> 5) + i * 8, colo = tid & 31;
        out[(size_t)(c0 + rowo) * R + r0 + colo] = f2bf(tile[colo][rowo]);
    }
}

// ---------------------------------------------------------------------------
// V transpose direct: Vt[b][kh][h][s] <- fresh (QKVh) or v_cache
// ---------------------------------------------------------------------------
__global__ void vtrans2(const unsigned short* __restrict__ QKVh,
                        const float* __restrict__ vc,
                        unsigned short* __restrict__ Vt,
                        const int* __restrict__ cur_ptr)
{
    int gid = blockIdx.x * 256 + threadIdx.x;
    int h  = gid & 127;
    int s8 = ((gid >> 7) & 255) * 8;
    int kh = (gid >> 15) & 7;
    int b  = gid >> 18;
    int cur = cur_ptr[0], curT = cur + Tc;
    unsigned short tmp[8];
#pragma unroll
    for (int e = 0; e < 8; ++e) {
        int s = s8 + e;
        unsigned short v;
        if (s >= cur && s < curT)
            v = QKVh[(size_t)(b * Tc + (s - cur)) * 4096 + 3072 + kh * Hc + h];
        else
            v = f2bf(vc[((size_t)(b * Sc + s) * KHc + kh) * Hc + h]);
        tmp[e] = v;
    }
    *(uint4*)&Vt[(((size_t)b * KHc + kh) * Hc + h) * Sc + s8] = *(uint4*)tmp;
}

// ---------------------------------------------------------------------------
// bf16 MFMA GEMM (m97 structure): C[M,N] = A[M,K] * BT[N,K]^T.
// ---------------------------------------------------------------------------
__global__ __launch_bounds__(256, 2) void gemm_mfma(const unsigned short* __restrict__ A,
                                                    const unsigned short* __restrict__ BT,
                                                    void* __restrict__ Cout,
                                                    int M, int N, int K, int out_fp32)
{
    __shared__ __align__(16) unsigned short As[128 * 32];
    __shared__ __align__(16) unsigned short Bs[128 * 32];
    int tid = threadIdx.x;
    int lane = tid & 63, w = tid >> 6;
    int quad = lane >> 4, l15 = lane & 15;
    int bm = blockIdx.y * 128, bn = blockIdx.x * 128;
    int wm = (w >> 1) * 64, wn = (w & 1) * 64;

    int srow = lane >> 2;
    int pl   = lane & 3;
    int sw   = (quad ^ ((l15 >> 1) & 3)) * 8;

    float4v acc[16];
#pragma unroll
    for (int i = 0; i < 16; ++i) acc[i] = (float4v)0.f;

    for (int k0 = 0; k0 < K; k0 += 32) {
        __syncthreads();
#pragma unroll
        for (int c = 0; c < 2; ++c) {
            int j = w * 2 + c;
            int row = j * 16 + srow;
            int pg = pl ^ ((row >> 1) & 3);
            __builtin_amdgcn_global_load_lds(
                (__attribute__((address_space(1))) void*)(A + (size_t)(bm + row) * K + k0 + pg * 8),
                (__attribute__((address_space(3))) void*)(As + j * 512), 16, 0, 0);
            __builtin_amdgcn_global_load_lds(
                (__attribute__((address_space(1))) void*)(BT + (size_t)(bn + row) * K + k0 + pg * 8),
                (__attribute__((address_space(3))) void*)(Bs + j * 512), 16, 0, 0);
        }
        __syncthreads();
        short8 af[4];
#pragma unroll
        for (int mi = 0; mi < 4; ++mi)
            af[mi] = *(const short8*)&As[(wm + mi * 16 + l15) * 32 + sw];
#pragma unroll
        for (int ni = 0; ni < 4; ++ni) {
            short8 bf = *(const short8*)&Bs[(wn + ni * 16 + l15) * 32 + sw];
#pragma unroll
            for (int mi = 0; mi < 4; ++mi)
                acc[mi * 4 + ni] = __builtin_amdgcn_mfma_f32_16x16x32_bf16(af[mi], bf, acc[mi * 4 + ni], 0, 0, 0);
        }
    }

#pragma unroll
    for (int mi = 0; mi < 4; ++mi)
#pragma unroll
        for (int ni = 0; ni < 4; ++ni)
#pragma unroll
            for (int reg = 0; reg < 4; ++reg) {
                int row = bm + wm + mi * 16 + quad * 4 + reg;
                int col = bn + wn + ni * 16 + l15;
                float v = acc[mi * 4 + ni][reg];
                if (out_fp32) ((float*)Cout)[(size_t)row * N + col] = v;
                else ((unsigned short*)Cout)[(size_t)row * N + col] = f2bf(v);
            }
}

// ---------------------------------------------------------------------------
// RMSNorm + RoPE on fused QKV buffer (ld=4096). slot 0..15: Q in-place;
// 16..23: K -> Kall[cur+t].
// ---------------------------------------------------------------------------
__global__ __launch_bounds__(256) void norm_rope(unsigned short* __restrict__ QKVh,
                                                 unsigned short* __restrict__ Kall,
                                                 const float* __restrict__ qw,
                                                 const float* __restrict__ kw,
                                                 const int* __restrict__ seg,
                                                 const int* __restrict__ meta,
                                                 const int* __restrict__ cur_ptr)
{
    int rowid = blockIdx.x * 4 + (threadIdx.x >> 6);
    int lane = threadIdx.x & 63;
    int hh = rowid % 24;
    int bt = rowid / 24;
    int t = bt & (Tc - 1);
    int b = bt >> 11;
    int cur = cur_ptr[0];

    const unsigned short* in;
    unsigned short* out;
    const float* wt;
    if (hh < 16) {
        unsigned short* p = QKVh + (size_t)bt * 4096 + hh * Hc;
        in = p; out = p; wt = qw;
    } else {
        int kh = hh - 16;
        in = QKVh + (size_t)bt * 4096 + 2048 + kh * Hc;
        out = Kall + (((size_t)b * Sc + cur + t) * KHc + kh) * Hc;
        wt = kw;
    }
    float v1 = bf2f(in[lane]), v2 = bf2f(in[lane + 64]);
    float ssq = v1 * v1 + v2 * v2;
#pragma unroll
    for (int off = 1; off < 64; off <<= 1) ssq += __shfl_xor(ssq, off);
    float rinv = rsqrtf(ssq * (1.0f / Hc) + EPSc);

    int sg = seg[bt];
    long long pos = (sg != 0) ? (long long)(t - meta[b]) : (long long)(1 << 30);
    float posf = (float)(pos + (long long)cur);
    float inv_freq = exp2f(-(float)lane * (19.931568569324174f / 64.0f));
    float s, c;
    sincosf(posf * inv_freq, &s, &c);

    float n1 = wt[lane] * v1 * rinv;
    float n2 = wt[lane + 64] * v2 * rinv;
    out[lane]      = f2bf(n1 * c - n2 * s);
    out[lane + 64] = f2bf(n2 * c + n1 * s);
}

// ---------------------------------------------------------------------------
// MFMA flash attention: fixed-max softmax + global_load_lds staging into
// unpadded XOR-swizzled LDS (conflict-free frag reads, no VGPR round-trip).
// Block: 256 thr, 128 q-rows, S-chunks of 64, causal chunk skip + qt pairing.
// LDS 50 KB -> 3 blocks/CU; inter-block overlap hides the staging drain.
// ---------------------------------------------------------------------------
__global__ __launch_bounds__(256, 2) void flash_mfma(const unsigned short* __restrict__ Qb,
                                                     const unsigned short* __restrict__ Kall,
                                                     const unsigned short* __restrict__ Vt,
                                                     const int* __restrict__ seg,
                                                     const int* __restrict__ meta,
                                                     const int* __restrict__ cur_ptr,
                                                     unsigned short* __restrict__ Ob)
{
    __shared__ __align__(16) unsigned short Ks[64 * 128];    // [s][h], swizzled parts
    __shared__ __align__(16) unsigned short Vs[128 * 64];    // [h][s], swizzled parts
    __shared__ __align__(16) unsigned short Ps[128 * 72];    // [qrow][s], padded

    int tid = threadIdx.x;
    int lane = tid & 63, w = tid >> 6;
    int quad = lane >> 4, l15 = lane & 15;
    int bid = blockIdx.x;
    int raw = bid & 15;
    int n  = (bid >> 4) & 15;
    int b  = bid >> 8;
    int qt = (b == 0) ? raw : (15 - raw);
    int kh = n >> 1;
    int cur = cur_ptr[0];
    int startb = meta[Bc + b];
    int curT = cur + Tc;
    int t0 = qt * 128 + w * 32;

    // Q fragments (A-layout)
    short8 qf[2][4];
#pragma unroll
    for (int mi = 0; mi < 2; ++mi)
#pragma unroll
        for (int ks = 0; ks < 4; ++ks) {
            int row = t0 + mi * 16 + l15;
            U16x8 u;
            u.u = *(const uint4*)&Qb[(size_t)(b * Tc + row) * 4096 + n * Hc + ks * 32 + quad * 8];
            qf[mi][ks] = u.s8;
        }

    int code = 0, ct[8];
#pragma unroll
    for (int mi = 0; mi < 2; ++mi)
#pragma unroll
        for (int reg = 0; reg < 4; ++reg) {
            int idx = mi * 4 + reg;
            int trow = t0 + mi * 16 + quad * 4 + reg;
            int sg = seg[b * Tc + trow];
            int cls = (sg == 0) ? 0 : ((sg == 1) ? 1 : 2);
            code |= cls << (2 * idx);
            ct[idx] = cur + trow;
        }
    bool allseg1 = (code == 0x5555);

    float lsum[8];
#pragma unroll
    for (int i = 0; i < 8; ++i) lsum[i] = 0.f;
    float4v o[16];
#pragma unroll
    for (int i = 0; i < 16; ++i) o[i] = (float4v)0.f;

    int s_end = min(Sc, cur + qt * 128 + 128);
    int nch = (s_end + 63) >> 6;

    // --- staging geometry (per wave: 4 K-instrs + 4 V-instrs per chunk) ---
    // K: wave-chunk j = w*4+i covers rows j*4..j*4+3; lane: row j*4+(lane>>4),
    //    LDS part pl=lane&15, global part pg = pl ^ ((row>>1)&7)
    const size_t kstride = (size_t)KHc * Hc;           // elems per s
    const unsigned short* kptr[4];
    unsigned short* kdst[4];
#pragma unroll
    for (int i = 0; i < 4; ++i) {
        int j = w * 4 + i;
        int row = j * 4 + (lane >> 4);
        int pl = lane & 15;
        int pg = pl ^ ((row >> 1) & 7);
        kptr[i] = Kall + (size_t)b * Sc * kstride + (size_t)row * kstride + kh * Hc + pg * 8;
        kdst[i] = Ks + j * 512;
    }
    // V: wave-chunk j covers h rows j*8..j*8+7; lane: h = j*8+(lane>>3),
    //    pl = lane&7, pg = pl ^ ((h>>1)&7)
    const unsigned short* vptr[4];
    unsigned short* vdst[4];
#pragma unroll
    for (int i = 0; i < 4; ++i) {
        int j = w * 4 + i;
        int h = j * 8 + (lane >> 3);
        int pl = lane & 7;
        int pg = pl ^ ((h >> 1) & 7);
        vptr[i] = Vt + ((size_t)b * KHc + kh) * (size_t)Hc * Sc + (size_t)h * Sc + pg * 8;
        vdst[i] = Vs + j * 512;
    }
    int sw3 = (l15 >> 1) & 7;   // frag-read XOR

    for (int c = 0; c < nch; ++c) {
        int s0 = c * 64;
        // stage chunk c (async, no VGPR round-trip)
#pragma unroll
        for (int i = 0; i < 4; ++i) {
            __builtin_amdgcn_global_load_lds(
                (__attribute__((address_space(1))) void*)(kptr[i] + (size_t)s0 * kstride),
                (__attribute__((address_space(3))) void*)kdst[i], 16, 0, 0);
            __builtin_amdgcn_global_load_lds(
                (__attribute__((address_space(1))) void*)(vptr[i] + s0),
                (__attribute__((address_space(3))) void*)vdst[i], 16, 0, 0);
        }
        __syncthreads();   // vmcnt(0) drain + sync: chunk landed

        // QK^T
        float4v sacc[2][4];
#pragma unroll
        for (int mi = 0; mi < 2; ++mi)
#pragma unroll
            for (int j = 0; j < 4; ++j) sacc[mi][j] = (float4v)0.f;
#pragma unroll
        for (int j = 0; j < 4; ++j) {
#pragma unroll
            for (int ks = 0; ks < 4; ++ks) {
                short8 kf = *(const short8*)&Ks[(j * 16 + l15) * 128 + ((ks * 4 + quad) ^ sw3) * 8];
                sacc[0][j] = __builtin_amdgcn_mfma_f32_16x16x32_bf16(qf[0][ks], kf, sacc[0][j], 0, 0, 0);
                sacc[1][j] = __builtin_amdgcn_mfma_f32_16x16x32_bf16(qf[1][ks], kf, sacc[1][j], 0, 0, 0);
            }
        }

        bool fullok = allseg1 && (s0 >= startb) && (s0 + 63 <= cur + t0) && (s0 + 63 < curT);

        // fixed-max softmax: p = exp2(score * SCALE2)
#pragma unroll
        for (int mi = 0; mi < 2; ++mi) {
#pragma unroll
            for (int reg = 0; reg < 4; ++reg) {
                int idx = mi * 4 + reg;
                int prow = w * 32 + mi * 16 + quad * 4 + reg;
                if (fullok) {
#pragma unroll
                    for (int j = 0; j < 4; ++j) {
                        float p = exp2f(sacc[mi][j][reg] * SCALE2);
                        lsum[idx] += p;
                        Ps[prow * 72 + j * 16 + l15] = f2bf(p);
                    }
                } else {
                    int ctv = ct[idx];
                    int clsv = (code >> (2 * idx)) & 3;
#pragma unroll
                    for (int j = 0; j < 4; ++j) {
                        int s = s0 + j * 16 + l15;
                        int kvseg = (s >= startb && s < curT) ? 1 : 0;
                        bool ok = (s <= ctv) && (clsv == kvseg);
                        float arg = ok ? sacc[mi][j][reg] * SCALE2 : -1e30f;
                        float p = exp2f(arg);
                        lsum[idx] += p;
                        Ps[prow * 72 + j * 16 + l15] = f2bf(p);
                    }
                }
            }
        }

        // PV (Ps rows are per-wave: no barrier needed between softmax and PV)
#pragma unroll
        for (int kk = 0; kk < 2; ++kk) {
            short8 pf0 = *(const short8*)&Ps[(w * 32 + l15) * 72 + kk * 32 + quad * 8];
            short8 pf1 = *(const short8*)&Ps[(w * 32 + 16 + l15) * 72 + kk * 32 + quad * 8];
#pragma unroll
            for (int nt = 0; nt < 8; ++nt) {
                short8 vf = *(const short8*)&Vs[(nt * 16 + l15) * 64 + ((kk * 4 + quad) ^ sw3) * 8];
                o[nt]     = __builtin_amdgcn_mfma_f32_16x16x32_bf16(pf0, vf, o[nt], 0, 0, 0);
                o[8 + nt] = __builtin_amdgcn_mfma_f32_16x16x32_bf16(pf1, vf, o[8 + nt], 0, 0, 0);
            }
        }
        __syncthreads();   // WAR: next staging overwrites Ks/Vs
    }

    // final l reduction across the 16 lanes of each quad-row
#pragma unroll
    for (int idx = 0; idx < 8; ++idx) {
        float l = lsum[idx];
        l += __shfl_xor(l, 1);
        l += __shfl_xor(l, 2);
        l += __shfl_xor(l, 4);
        l += __shfl_xor(l, 8);
        lsum[idx] = (l > 0.f) ? (1.0f / l) : 0.f;
    }

#pragma unroll
    for (int mi = 0; mi < 2; ++mi)
#pragma unroll
        for (int reg = 0; reg < 4; ++reg) {
            float linv = lsum[mi * 4 + reg];
            int trow = t0 + mi * 16 + quad * 4 + reg;
            size_t base = ((size_t)(b * Tc + trow) * Nc + n) * Hc;
#pragma unroll
            for (int nt = 0; nt < 8; ++nt)
                Ob[base + nt * 16 + l15] = f2bf(o[mi * 8 + nt][reg] * linv);
        }
}

// ---------------------------------------------------------------------------
extern "C" void kernel_launch(void* const* d_in, const int* in_sizes, int n_in,
                              void* d_out, int out_size, void* d_ws, size_t ws_size,
                              hipStream_t stream)
{
    const float* x        = (const float*)d_in[0];
    const float* q_w      = (const float*)d_in[1];
    const float* k_w      = (const float*)d_in[2];
    const float* v_w      = (const float*)d_in[3];
    const float* o_w      = (const float*)d_in[4];
    const float* q_norm_w = (const float*)d_in[5];
    const float* k_norm_w = (const float*)d_in[6];
    const float* k_cache  = (const float*)d_in[7];
    const float* v_cache  = (const float*)d_in[8];
    const int*   seg      = (const int*)d_in[9];
    const int*   startind = (const int*)d_in[10];
    const int*   cur_ptr  = (const int*)d_in[11];
    (void)in_sizes; (void)n_in; (void)out_size; (void)ws_size;

    char* base = (char*)d_ws;
    int* meta = (int*)base;                                          //      1024 B
    unsigned short* QKVh = (unsigned short*)(base + 1024);           // 33.55 MB [4096][4096]
    unsigned short* Kall = (unsigned short*)(base + 33555456);       //  8.39 MB [B][S][KH][H]
    unsigned short* Vt   = (unsigned short*)(base + 41944064);       //  8.39 MB [B][KH][H][S]
    unsigned short* xb   = (unsigned short*)(base + 50332672);       // 16.78 MB; reused as Ob
    unsigned short* qkvwT= (unsigned short*)(base + 67109888);       // 16.78 MB [4096][2048] (Q|K|V rows)
    unsigned short* owT  = (unsigned short*)(base + 83887104);       //  8.39 MB [2048][2048]
    unsigned short* Ob   = xb;

    meta_kernel<<<Bc, 256, 0, stream>>>(seg, startind, meta);

    cast_bf16<<<4096, 256, 0, stream>>>(x, xb);
    transpose_cast<<<dim3(64, 64), 256, 0, stream>>>(q_w, qkvwT, Dc, Nc * Hc);
    transpose_cast<<<dim3(32, 64), 256, 0, stream>>>(k_w, qkvwT + (size_t)2048 * 2048, Dc, KHc * Hc);
    transpose_cast<<<dim3(32, 64), 256, 0, stream>>>(v_w, qkvwT + (size_t)3072 * 2048, Dc, KHc * Hc);
    transpose_cast<<<dim3(64, 64), 256, 0, stream>>>(o_w, owT, Nc * Hc, Dc);

    // fused QKV projection: [4096 x 2048] @ [2048 x 4096]
    gemm_mfma<<<dim3(32, 32), 256, 0, stream>>>(xb, qkvwT, QKVh, Bc * Tc, 4096, Dc, 0);

    norm_rope<<<Bc * Tc * 24 / 4, 256, 0, stream>>>(QKVh, Kall,
                                                    q_norm_w, k_norm_w, seg, meta, cur_ptr);

    fill_kcache<<<2048, 256, 0, stream>>>(k_cache, Kall, cur_ptr);
    vtrans2<<<2048, 256, 0, stream>>>(QKVh, v_cache, Vt, cur_ptr);

    flash_mfma<<<Bc * Nc * (Tc / 128), 256, 0, stream>>>(QKVh, Kall, Vt, seg, meta, cur_ptr, Ob);

    gemm_mfma<<<dim3(16, 32), 256, 0, stream>>>(Ob, owT, d_out, Bc * Tc, Dc, Nc * Hc, 1);
}

// Round 7
// 396.608 us; speedup vs baseline: 1.3142x; 1.0663x over previous
//
#include <hip/hip_runtime.h>
#include <hip/hip_fp16.h>
#include <climits>
#include <math.h>

#define Bc   2
#define Tc   2048
#define Dc   2048
#define Nc   16
#define KHc  8
#define Hc   128
#define Sc   2048

constexpr float EPSc   = 1e-6f;
constexpr float SCALE2 = 0.1275174477984469f;     // (1/sqrt(128)) * log2(e)

typedef short short8 __attribute__((ext_vector_type(8)));
typedef _Float16 half8 __attribute__((ext_vector_type(8)));
typedef __fp16 fp16x2 __attribute__((ext_vector_type(2)));
typedef float float4v __attribute__((ext_vector_type(4)));

union U16x8 { uint4 u; short8 s8; half8 h8; unsigned short us[8]; };
union H2U  { fp16x2 h; unsigned u; };
union S8H8 { short8 s; half8 h; };

__device__ __forceinline__ unsigned short f2bf(float f) {
    union { float f; unsigned u; } v; v.f = f;
    unsigned r = v.u + 0x7FFFu + ((v.u >> 16) & 1u);
    return (unsigned short)(r >> 16);
}
__device__ __forceinline__ float bf2f(unsigned short u) {
    union { unsigned u; float f; } v; v.u = ((unsigned)u) << 16;
    return v.f;
}

// ---------------------------------------------------------------------------
// prep: fused meta + x-cast + 4 weight transposes (12 launches -> 1)
// regions by blockIdx.x:
//   [0,2)            meta
//   [2, 2+4096)      cast x -> xb (bf16)
//   next 4096        q_w  [2048][2048] -> qkvwT rows 0..2047
//   next 2048        k_w  [2048][1024] -> qkvwT rows 2048..3071
//   next 2048        v_w  [2048][1024] -> qkvwT rows 3072..4095
//   next 4096        o_w  [2048][2048] -> owT
// ---------------------------------------------------------------------------
__device__ __forceinline__ void tc_body(const float* __restrict__ in,
                                        unsigned short* __restrict__ out,
                                        int R, int C, int bx, int by, int tid,
                                        float tile[32][33])
{
    int c0 = bx * 32, r0 = by * 32;
#pragma unroll
    for (int i = 0; i < 4; ++i) {
        int row = (tid >> 5) + i * 8, col = tid & 31;
        tile[row][col] = in[(size_t)(r0 + row) * C + c0 + col];
    }
    __syncthreads();
#pragma unroll
    for (int i = 0; i < 4; ++i) {
        int rowo = (tid >> 5) + i * 8, colo = tid & 31;
        out[(size_t)(c0 + rowo) * R + r0 + colo] = f2bf(tile[colo][rowo]);
    }
}

__global__ __launch_bounds__(256) void prep(const float* __restrict__ x,
                                            const float* __restrict__ qw,
                                            const float* __restrict__ kw,
                                            const float* __restrict__ vw,
                                            const float* __restrict__ ow,
                                            const int* __restrict__ seg,
                                            const int* __restrict__ start_ind,
                                            int* __restrict__ meta,
                                            unsigned short* __restrict__ xb,
                                            unsigned short* __restrict__ qkvwT,
                                            unsigned short* __restrict__ owT)
{
    __shared__ float tile[32][33];
    __shared__ int s_max, s_amax, s_nz;
    int id = blockIdx.x;
    int tid = threadIdx.x;

    if (id < Bc) {   // meta
        int b = id;
        if (tid == 0) { s_max = INT_MIN; s_amax = Tc; s_nz = Tc; }
        __syncthreads();
        int lmax = INT_MIN;
        for (int t = tid; t < Tc; t += 256) lmax = max(lmax, seg[b * Tc + t]);
        atomicMax(&s_max, lmax);
        __syncthreads();
        int mv = s_max;
        int lamax = Tc, lnz = Tc;
        for (int t = tid; t < Tc; t += 256) {
            int v = seg[b * Tc + t];
            if (v == mv) lamax = min(lamax, t);
            if (v != 0)  lnz   = min(lnz, t);
        }
        atomicMin(&s_amax, lamax);
        atomicMin(&s_nz, lnz);
        __syncthreads();
        if (tid == 0) {
            meta[b] = s_amax;
            int st = start_ind[b];
            meta[Bc + b] = (st < 0) ? s_nz : st;
        }
        return;
    }
    id -= Bc;
    if (id < 4096) {   // cast x
        size_t base = ((size_t)id * 256 + tid) * 8;
        float4 a = *(const float4*)&x[base];
        float4 b = *(const float4*)&x[base + 4];
        U16x8 o;
        o.us[0] = f2bf(a.x); o.us[1] = f2bf(a.y); o.us[2] = f2bf(a.z); o.us[3] = f2bf(a.w);
        o.us[4] = f2bf(b.x); o.us[5] = f2bf(b.y); o.us[6] = f2bf(b.z); o.us[7] = f2bf(b.w);
        *(uint4*)&xb[base] = o.u;
        return;
    }
    id -= 4096;
    if (id < 4096) { tc_body(qw, qkvwT, 2048, 2048, id & 63, id >> 6, tid, tile); return; }
    id -= 4096;
    if (id < 2048) { tc_body(kw, qkvwT + (size_t)2048 * 2048, 2048, 1024, id & 31, id >> 5, tid, tile); return; }
    id -= 2048;
    if (id < 2048) { tc_body(vw, qkvwT + (size_t)3072 * 2048, 2048, 1024, id & 31, id >> 5, tid, tile); return; }
    id -= 2048;
    tc_body(ow, owT, 2048, 2048, id & 63, id >> 6, tid, tile);
}

// ---------------------------------------------------------------------------
// bf16 MFMA GEMM (m97 structure): C[M,N] = A[M,K] * BT[N,K]^T.
// ---------------------------------------------------------------------------
__global__ __launch_bounds__(256, 2) void gemm_mfma(const unsigned short* __restrict__ A,
                                                    const unsigned short* __restrict__ BT,
                                                    void* __restrict__ Cout,
                                                    int M, int N, int K, int out_fp32)
{
    __shared__ __align__(16) unsigned short As[128 * 32];
    __shared__ __align__(16) unsigned short Bs[128 * 32];
    int tid = threadIdx.x;
    int lane = tid & 63, w = tid >> 6;
    int quad = lane >> 4, l15 = lane & 15;
    int bm = blockIdx.y * 128, bn = blockIdx.x * 128;
    int wm = (w >> 1) * 64, wn = (w & 1) * 64;

    int srow = lane >> 2;
    int pl   = lane & 3;
    int sw   = (quad ^ ((l15 >> 1) & 3)) * 8;

    float4v acc[16];
#pragma unroll
    for (int i = 0; i < 16; ++i) acc[i] = (float4v)0.f;

    for (int k0 = 0; k0 < K; k0 += 32) {
        __syncthreads();
#pragma unroll
        for (int c = 0; c < 2; ++c) {
            int j = w * 2 + c;
            int row = j * 16 + srow;
            int pg = pl ^ ((row >> 1) & 3);
            __builtin_amdgcn_global_load_lds(
                (__attribute__((address_space(1))) void*)(A + (size_t)(bm + row) * K + k0 + pg * 8),
                (__attribute__((address_space(3))) void*)(As + j * 512), 16, 0, 0);
            __builtin_amdgcn_global_load_lds(
                (__attribute__((address_space(1))) void*)(BT + (size_t)(bn + row) * K + k0 + pg * 8),
                (__attribute__((address_space(3))) void*)(Bs + j * 512), 16, 0, 0);
        }
        __syncthreads();
        short8 af[4];
#pragma unroll
        for (int mi = 0; mi < 4; ++mi)
            af[mi] = *(const short8*)&As[(wm + mi * 16 + l15) * 32 + sw];
#pragma unroll
        for (int ni = 0; ni < 4; ++ni) {
            short8 bf = *(const short8*)&Bs[(wn + ni * 16 + l15) * 32 + sw];
#pragma unroll
            for (int mi = 0; mi < 4; ++mi)
                acc[mi * 4 + ni] = __builtin_amdgcn_mfma_f32_16x16x32_bf16(af[mi], bf, acc[mi * 4 + ni], 0, 0, 0);
        }
    }

#pragma unroll
    for (int mi = 0; mi < 4; ++mi)
#pragma unroll
        for (int ni = 0; ni < 4; ++ni)
#pragma unroll
            for (int reg = 0; reg < 4; ++reg) {
                int row = bm + wm + mi * 16 + quad * 4 + reg;
                int col = bn + wn + ni * 16 + l15;
                float v = acc[mi * 4 + ni][reg];
                if (out_fp32) ((float*)Cout)[(size_t)row * N + col] = v;
                else ((unsigned short*)Cout)[(size_t)row * N + col] = f2bf(v);
            }
}

// ---------------------------------------------------------------------------
// post: fused norm_rope (Q in-place, K -> Kall) + K-cache fill + V transpose
// regions by blockIdx.x:
//   [0, 24576)         norm_rope (4 rows/block over Bc*Tc*24 rows)
//   next 2048          fill Kall from k_cache (rows outside [cur,cur+T))
//   next 2048          vtrans: Vt[b][kh][h][s] (f16) <- fresh QKVh or v_cache
// ---------------------------------------------------------------------------
__global__ __launch_bounds__(256) void post(unsigned short* __restrict__ QKVh,
                                            unsigned short* __restrict__ Kall,
                                            unsigned short* __restrict__ Vt,
                                            const float* __restrict__ qw,
                                            const float* __restrict__ kw,
                                            const int* __restrict__ seg,
                                            const int* __restrict__ meta,
                                            const int* __restrict__ cur_ptr,
                                            const float* __restrict__ kc,
                                            const float* __restrict__ vc)
{
    int id = blockIdx.x;
    int tid = threadIdx.x;
    int cur = cur_ptr[0];

    if (id < 24576) {   // norm + rope
        int rowid = id * 4 + (tid >> 6);
        int lane = tid & 63;
        int hh = rowid % 24;
        int bt = rowid / 24;
        int t = bt & (Tc - 1);
        int b = bt >> 11;

        const unsigned short* in;
        unsigned short* out;
        const float* wt;
        if (hh < 16) {
            unsigned short* p = QKVh + (size_t)bt * 4096 + hh * Hc;
            in = p; out = p; wt = qw;
        } else {
            int kh = hh - 16;
            in = QKVh + (size_t)bt * 4096 + 2048 + kh * Hc;
            out = Kall + (((size_t)b * Sc + cur + t) * KHc + kh) * Hc;
            wt = kw;
        }
        float v1 = bf2f(in[lane]), v2 = bf2f(in[lane + 64]);
        float ssq = v1 * v1 + v2 * v2;
#pragma unroll
        for (int off = 1; off < 64; off <<= 1) ssq += __shfl_xor(ssq, off);
        float rinv = rsqrtf(ssq * (1.0f / Hc) + EPSc);

        int sg = seg[bt];
        long long pos = (sg != 0) ? (long long)(t - meta[b]) : (long long)(1 << 30);
        float posf = (float)(pos + (long long)cur);
        float inv_freq = exp2f(-(float)lane * (19.931568569324174f / 64.0f));
        float s, c;
        sincosf(posf * inv_freq, &s, &c);

        float n1 = wt[lane] * v1 * rinv;
        float n2 = wt[lane + 64] * v2 * rinv;
        out[lane]      = f2bf(n1 * c - n2 * s);
        out[lane + 64] = f2bf(n2 * c + n1 * s);
        return;
    }
    id -= 24576;
    if (id < 2048) {   // K cache fill
        size_t base = ((size_t)id * 256 + tid) * 8;
        int s = (int)((base >> 10) & (Sc - 1));
        if (s >= cur && s < cur + Tc) return;
        float4 a = *(const float4*)&kc[base];
        float4 b = *(const float4*)&kc[base + 4];
        U16x8 o;
        o.us[0] = f2bf(a.x); o.us[1] = f2bf(a.y); o.us[2] = f2bf(a.z); o.us[3] = f2bf(a.w);
        o.us[4] = f2bf(b.x); o.us[5] = f2bf(b.y); o.us[6] = f2bf(b.z); o.us[7] = f2bf(b.w);
        *(uint4*)&Kall[base] = o.u;
        return;
    }
    id -= 2048;
    {   // V transpose -> f16
        int gid = id * 256 + tid;
        int h  = gid & 127;
        int s8 = ((gid >> 7) & 255) * 8;
        int kh = (gid >> 15) & 7;
        int b  = gid >> 18;
        int curT = cur + Tc;
        unsigned short tmp[8];
#pragma unroll
        for (int e = 0; e < 8; ++e) {
            int s = s8 + e;
            float f;
            if (s >= cur && s < curT)
                f = bf2f(QKVh[(size_t)(b * Tc + (s - cur)) * 4096 + 3072 + kh * Hc + h]);
            else
                f = vc[((size_t)(b * Sc + s) * KHc + kh) * Hc + h];
            tmp[e] = __half_as_ushort(__float2half(f));
        }
        *(uint4*)&Vt[(((size_t)b * KHc + kh) * Hc + h) * Sc + s8] = *(uint4*)tmp;
    }
}

// ---------------------------------------------------------------------------
// MFMA flash attention, S^T formulation:
//   S^T = K·Q^T  (A=K-frag, B=Q-frag)  -> C-layout col=q(l15), row=s(quad*4+reg)
//   softmax per-lane (mask meta per l15), packed f16 b64 stores of P[q][s]
//   O^T = V^T·P^T (A=Vs[h][s] f16, B=Ps[q][s] f16) -> col=q, row=h
// Fixed-max softmax (|score|<=11.4 after RMSNorm). Chunk 64, causal skip,
// qt pairing, global_load_lds staging into XOR-swizzled LDS.
// ---------------------------------------------------------------------------
__global__ __launch_bounds__(256, 2) void flash_mfma(const unsigned short* __restrict__ Qb,
                                                     const unsigned short* __restrict__ Kall,
                                                     const unsigned short* __restrict__ Vt,
                                                     const int* __restrict__ seg,
                                                     const int* __restrict__ meta,
                                                     const int* __restrict__ cur_ptr,
                                                     unsigned short* __restrict__ Ob)
{
    __shared__ __align__(16) unsigned short Ks[64 * 128];    // bf16 [s][h], parts swizzled
    __shared__ __align__(16) unsigned short Vs[128 * 64];    // f16  [h][s], parts swizzled
    __shared__ __align__(16) unsigned short Ps[128 * 72];    // f16  [q][s], padded

    int tid = threadIdx.x;
    int lane = tid & 63, w = tid >> 6;
    int quad = lane >> 4, l15 = lane & 15;
    int bid = blockIdx.x;
    int raw = bid & 15;
    int n  = (bid >> 4) & 15;
    int b  = bid >> 8;
    int qt = (b == 0) ? raw : (15 - raw);
    int kh = n >> 1;
    int cur = cur_ptr[0];
    int startb = meta[Bc + b];
    int curT = cur + Tc;
    int t0 = qt * 128 + w * 32;

    // Q fragments (B-operand layout == A layout: l15 -> q, quad*8+j -> h)
    short8 qf[2][4];
#pragma unroll
    for (int qtile = 0; qtile < 2; ++qtile)
#pragma unroll
        for (int ks = 0; ks < 4; ++ks) {
            int row = t0 + qtile * 16 + l15;
            U16x8 u;
            u.u = *(const uint4*)&Qb[(size_t)(b * Tc + row) * 4096 + n * Hc + ks * 32 + quad * 8];
            qf[qtile][ks] = u.s8;
        }

    // per-lane mask metadata (q = l15-indexed)
    int ctq[2], clsq[2];
#pragma unroll
    for (int qtile = 0; qtile < 2; ++qtile) {
        int trow = t0 + qtile * 16 + l15;
        int sg = seg[b * Tc + trow];
        clsq[qtile] = (sg == 0) ? 0 : ((sg == 1) ? 1 : 2);
        ctq[qtile] = cur + trow;
    }
    unsigned long long m0 = __ballot(clsq[0] == 1);
    unsigned long long m1 = __ballot(clsq[1] == 1);
    bool allseg1 = ((m0 & m1) == 0xFFFFFFFFFFFFFFFFull);

    float lsum[2] = {0.f, 0.f};
    float4v oT[16];   // [htile][qtile] -> htile*2+qtile
#pragma unroll
    for (int i = 0; i < 16; ++i) oT[i] = (float4v)0.f;

    int s_end = min(Sc, cur + qt * 128 + 128);
    int nch = (s_end + 63) >> 6;

    // staging geometry (per wave: 4 K + 4 V global_load_lds per chunk)
    const size_t kstride = (size_t)KHc * Hc;
    const unsigned short* kptr[4];
    unsigned short* kdst[4];
#pragma unroll
    for (int i = 0; i < 4; ++i) {
        int j = w * 4 + i;
        int row = j * 4 + (lane >> 4);
        int pl = lane & 15;
        int pg = pl ^ ((row >> 1) & 7);
        kptr[i] = Kall + (size_t)b * Sc * kstride + (size_t)row * kstride + kh * Hc + pg * 8;
        kdst[i] = Ks + j * 512;
    }
    const unsigned short* vptr[4];
    unsigned short* vdst[4];
#pragma unroll
    for (int i = 0; i < 4; ++i) {
        int j = w * 4 + i;
        int h = j * 8 + (lane >> 3);
        int pl = lane & 7;
        int pg = pl ^ ((h >> 1) & 7);
        vptr[i] = Vt + ((size_t)b * KHc + kh) * (size_t)Hc * Sc + (size_t)h * Sc + pg * 8;
        vdst[i] = Vs + j * 512;
    }
    int sw3 = (l15 >> 1) & 7;
    unsigned short* psrow0 = Ps + (w * 32 + l15) * 72;          // qtile 0 row
    unsigned short* psrow1 = Ps + (w * 32 + 16 + l15) * 72;     // qtile 1 row

    for (int c = 0; c < nch; ++c) {
        int s0 = c * 64;
#pragma unroll
        for (int i = 0; i < 4; ++i) {
            __builtin_amdgcn_global_load_lds(
                (__attribute__((address_space(1))) void*)(kptr[i] + (size_t)s0 * kstride),
                (__attribute__((address_space(3))) void*)kdst[i], 16, 0, 0);
            __builtin_amdgcn_global_load_lds(
                (__attribute__((address_space(1))) void*)(vptr[i] + s0),
                (__attribute__((address_space(3))) void*)vdst[i], 16, 0, 0);
        }
        __syncthreads();

        // S^T = K·Q^T : st[stile][qtile], row=s, col=q
        float4v st[4][2];
#pragma unroll
        for (int i = 0; i < 4; ++i) { st[i][0] = (float4v)0.f; st[i][1] = (float4v)0.f; }
#pragma unroll
        for (int ks = 0; ks < 4; ++ks) {
#pragma unroll
            for (int stile = 0; stile < 4; ++stile) {
                short8 kf = *(const short8*)&Ks[(stile * 16 + l15) * 128 + ((ks * 4 + quad) ^ sw3) * 8];
                st[stile][0] = __builtin_amdgcn_mfma_f32_16x16x32_bf16(kf, qf[0][ks], st[stile][0], 0, 0, 0);
                st[stile][1] = __builtin_amdgcn_mfma_f32_16x16x32_bf16(kf, qf[1][ks], st[stile][1], 0, 0, 0);
            }
        }

        bool fullok = allseg1 && (s0 >= startb) && (s0 + 63 <= cur + t0) && (s0 + 63 < curT);

        // softmax: p = exp2(score*SCALE2); pack 4 s-consecutive f16 -> b64 store
#pragma unroll
        for (int stile = 0; stile < 4; ++stile) {
#pragma unroll
            for (int qtile = 0; qtile < 2; ++qtile) {
                float p0, p1, p2, p3;
                if (fullok) {
                    p0 = exp2f(st[stile][qtile][0] * SCALE2);
                    p1 = exp2f(st[stile][qtile][1] * SCALE2);
                    p2 = exp2f(st[stile][qtile][2] * SCALE2);
                    p3 = exp2f(st[stile][qtile][3] * SCALE2);
                } else {
                    int ctv = ctq[qtile], clsv = clsq[qtile];
                    float pp[4];
#pragma unroll
                    for (int reg = 0; reg < 4; ++reg) {
                        int s = s0 + stile * 16 + quad * 4 + reg;
                        int kvseg = (s >= startb && s < curT) ? 1 : 0;
                        bool ok = (s <= ctv) && (clsv == kvseg);
                        pp[reg] = exp2f(ok ? st[stile][qtile][reg] * SCALE2 : -1e30f);
                    }
                    p0 = pp[0]; p1 = pp[1]; p2 = pp[2]; p3 = pp[3];
                }
                lsum[qtile] += (p0 + p1) + (p2 + p3);
                H2U a, d;
                a.h = __builtin_amdgcn_cvt_pkrtz(p0, p1);
                d.h = __builtin_amdgcn_cvt_pkrtz(p2, p3);
                uint2 pk; pk.x = a.u; pk.y = d.u;
                unsigned short* pr = (qtile == 0) ? psrow0 : psrow1;
                *(uint2*)&pr[stile * 16 + quad * 4] = pk;
            }
        }

        // O^T += V^T · P^T   (A = Vs f16, B = Ps f16) — own wave's Ps rows only
#pragma unroll
        for (int kk = 0; kk < 2; ++kk) {
            S8H8 pf0, pf1;
            pf0.s = *(const short8*)&psrow0[kk * 32 + quad * 8];
            pf1.s = *(const short8*)&psrow1[kk * 32 + quad * 8];
#pragma unroll
            for (int htile = 0; htile < 8; ++htile) {
                S8H8 vf;
                vf.s = *(const short8*)&Vs[(htile * 16 + l15) * 64 + ((kk * 4 + quad) ^ sw3) * 8];
                oT[htile * 2 + 0] = __builtin_amdgcn_mfma_f32_16x16x32_f16(vf.h, pf0.h, oT[htile * 2 + 0], 0, 0, 0);
                oT[htile * 2 + 1] = __builtin_amdgcn_mfma_f32_16x16x32_f16(vf.h, pf1.h, oT[htile * 2 + 1], 0, 0, 0);
            }
        }
        __syncthreads();   // WAR: next staging overwrites Ks/Vs
    }

    // l: sum across the 4 quads holding the same q (xor 16, 32)
    float linv[2];
#pragma unroll
    for (int qtile = 0; qtile < 2; ++qtile) {
        float l = lsum[qtile];
        l += __shfl_xor(l, 16);
        l += __shfl_xor(l, 32);
        linv[qtile] = (l > 0.f) ? (1.0f / l) : 0.f;
    }

    // epilogue: O^T col=q(l15), row=h(quad*4+reg) -> packed b64 bf16 stores
#pragma unroll
    for (int qtile = 0; qtile < 2; ++qtile) {
        int trow = t0 + qtile * 16 + l15;
        size_t base = ((size_t)(b * Tc + trow) * Nc + n) * Hc;
#pragma unroll
        for (int htile = 0; htile < 8; ++htile) {
            float4v v = oT[htile * 2 + qtile];
            unsigned short r0 = f2bf(v[0] * linv[qtile]);
            unsigned short r1 = f2bf(v[1] * linv[qtile]);
            unsigned short r2 = f2bf(v[2] * linv[qtile]);
            unsigned short r3 = f2bf(v[3] * linv[qtile]);
            uint2 pk;
            pk.x = (unsigned)r0 | ((unsigned)r1 << 16);
            pk.y = (unsigned)r2 | ((unsigned)r3 << 16);
            *(uint2*)&Ob[base + htile * 16 + quad * 4] = pk;
        }
    }
}

// ---------------------------------------------------------------------------
extern "C" void kernel_launch(void* const* d_in, const int* in_sizes, int n_in,
                              void* d_out, int out_size, void* d_ws, size_t ws_size,
                              hipStream_t stream)
{
    const float* x        = (const float*)d_in[0];
    const float* q_w      = (const float*)d_in[1];
    const float* k_w      = (const float*)d_in[2];
    const float* v_w      = (const float*)d_in[3];
    const float* o_w      = (const float*)d_in[4];
    const float* q_norm_w = (const float*)d_in[5];
    const float* k_norm_w = (const float*)d_in[6];
    const float* k_cache  = (const float*)d_in[7];
    const float* v_cache  = (const float*)d_in[8];
    const int*   seg      = (const int*)d_in[9];
    const int*   startind = (const int*)d_in[10];
    const int*   cur_ptr  = (const int*)d_in[11];
    (void)in_sizes; (void)n_in; (void)out_size; (void)ws_size;

    char* base = (char*)d_ws;
    int* meta = (int*)base;                                          //      1024 B
    unsigned short* QKVh = (unsigned short*)(base + 1024);           // 33.55 MB [4096][4096]
    unsigned short* Kall = (unsigned short*)(base + 33555456);       //  8.39 MB bf16 [B][S][KH][H]
    unsigned short* Vt   = (unsigned short*)(base + 41944064);       //  8.39 MB f16  [B][KH][H][S]
    unsigned short* xb   = (unsigned short*)(base + 50332672);       // 16.78 MB; reused as Ob
    unsigned short* qkvwT= (unsigned short*)(base + 67109888);       // 16.78 MB [4096][2048]
    unsigned short* owT  = (unsigned short*)(base + 83887104);       //  8.39 MB [2048][2048]
    unsigned short* Ob   = xb;

    // 1) fused prep: meta + cast + 4 transposes
    prep<<<Bc + 4096 + 4096 + 2048 + 2048 + 4096, 256, 0, stream>>>(
        x, q_w, k_w, v_w, o_w, seg, startind, meta, xb, qkvwT, owT);

    // 2) fused QKV projection: [4096 x 2048] @ [2048 x 4096]
    gemm_mfma<<<dim3(32, 32), 256, 0, stream>>>(xb, qkvwT, QKVh, Bc * Tc, 4096, Dc, 0);

    // 3) fused post: norm+rope, K-cache fill, V transpose (f16)
    post<<<24576 + 2048 + 2048, 256, 0, stream>>>(QKVh, Kall, Vt,
        q_norm_w, k_norm_w, seg, meta, cur_ptr, k_cache, v_cache);

    // 4) flash attention
    flash_mfma<<<Bc * Nc * (Tc / 128), 256, 0, stream>>>(QKVh, Kall, Vt, seg, meta, cur_ptr, Ob);

    // 5) O projection -> fp32 out
    gemm_mfma<<<dim3(16, 32), 256, 0, stream>>>(Ob, owT, d_out, Bc * Tc, Dc, Nc * Hc, 1);
}